// Round 1
// baseline (3026.602 us; speedup 1.0000x reference)
//
#include <hip/hip_runtime.h>
#include <math.h>

#define NN   100000
#define EE   800000
#define RR   6
#define BB   1000
#define HH   128
#define DD1  21
#define MM   (RR*NN)

static inline int ceil_div(int a, int b){ return (a+b-1)/b; }

__device__ __forceinline__ unsigned fenc(float f){
  unsigned u = __float_as_uint(f);
  return (u & 0x80000000u) ? ~u : (u | 0x80000000u);
}
__device__ __forceinline__ float fdec(unsigned u){
  return __uint_as_float((u & 0x80000000u) ? (u & 0x7fffffffu) : ~u);
}

// ---------------- CSR build ----------------
__global__ void k_count(const int* __restrict__ edges, int* __restrict__ cnt)
{
  int gid = blockIdx.x*256 + threadIdx.x;
  if (gid >= RR*EE) return;
  int r = gid / EE, e = gid - r*EE;
  int dst = edges[(size_t)r*2*EE + EE + e];
  atomicAdd(&cnt[r*NN + dst], 1);
}

#define SCB 256
#define SCI 4
__global__ void k_scan1(const int* __restrict__ in, int* __restrict__ out,
                        int* __restrict__ bsums, int M)
{
  __shared__ int sh[SCB];
  int base = blockIdx.x * (SCB*SCI);
  int t = threadIdx.x;
  int v[SCI]; int local = 0;
  #pragma unroll
  for (int i = 0; i < SCI; ++i) {
    int idx = base + t*SCI + i;
    v[i] = (idx < M) ? in[idx] : 0;
    local += v[i];
  }
  sh[t] = local;
  __syncthreads();
  for (int o = 1; o < SCB; o <<= 1) {
    int add = (t >= o) ? sh[t-o] : 0;
    __syncthreads();
    sh[t] += add;
    __syncthreads();
  }
  int excl = sh[t] - local;
  if (t == SCB-1) bsums[blockIdx.x] = sh[t];
  int run = excl;
  #pragma unroll
  for (int i = 0; i < SCI; ++i) {
    int idx = base + t*SCI + i;
    if (idx < M) out[idx] = run;
    run += v[i];
  }
}

__global__ void k_scan2(int* __restrict__ bsums, int NB)
{
  __shared__ int sh[SCB];
  int t = threadIdx.x;
  int carry = 0;
  for (int c = 0; c < NB; c += SCB) {
    int idx = c + t;
    int v = (idx < NB) ? bsums[idx] : 0;
    sh[t] = v;
    __syncthreads();
    for (int o = 1; o < SCB; o <<= 1) {
      int add = (t >= o) ? sh[t-o] : 0;
      __syncthreads();
      sh[t] += add;
      __syncthreads();
    }
    int incl = sh[t];
    int total = sh[SCB-1];
    if (idx < NB) bsums[idx] = carry + incl - v;
    carry += total;
    __syncthreads();
  }
}

__global__ void k_scan3(int* __restrict__ out, const int* __restrict__ bsums,
                        int M, int total)
{
  int gid = blockIdx.x*256 + threadIdx.x;
  if (gid < M) out[gid] += bsums[gid >> 10];
  if (gid == 0) out[M] = total;
}

__global__ void k_scatter(const int* __restrict__ edges, const int* __restrict__ off,
                          int* __restrict__ cur, int* __restrict__ elist)
{
  int gid = blockIdx.x*256 + threadIdx.x;
  if (gid >= RR*EE) return;
  int r = gid / EE, e = gid - r*EE;
  int src = edges[(size_t)r*2*EE + e];
  int dst = edges[(size_t)r*2*EE + EE + e];
  int slot = off[r*NN + dst] + atomicAdd(&cur[r*NN + dst], 1);
  elist[slot] = src;
}

// ---------------- feature prep ----------------
__global__ void k_featprep(const float* __restrict__ x_all, const float* __restrict__ pos_table,
                           float* __restrict__ x0)
{
  int gid = blockIdx.x*256 + threadIdx.x;
  if (gid >= NN*DD1) return;
  int nidx = gid / DD1, c = gid - nidx*DD1;
  float v;
  if (c < 13) {
    int sc = (c < 5) ? c : c + 1;
    v = x_all[nidx*14 + sc];
  } else {
    int pi = (int)x_all[nidx*14 + 5];
    pi = pi < 0 ? 0 : (pi > 23 ? 23 : pi);
    v = pos_table[pi*8 + (c - 13)];
  }
  x0[gid] = v;
}

// ---------------- GEMM + attention dot epilogue ----------------
// C[n,128] = A[n,K] @ W[K,128]; zs[n] = C[n]·a_s; zd[n] = C[n]·a_d
__global__ void k_gemm_att(const float* __restrict__ A, const float* __restrict__ W,
                           const float* __restrict__ a_s, const float* __restrict__ a_d,
                           float* __restrict__ C, float* __restrict__ zs, float* __restrict__ zd,
                           int n, int K)
{
  __shared__ float Ws[32][128];
  __shared__ float As[16][33];
  int row = threadIdx.x >> 4;    // 0..15
  int cg  = threadIdx.x & 15;    // 0..15
  int r0 = blockIdx.x * 16;
  float acc[8] = {0,0,0,0,0,0,0,0};
  for (int kc = 0; kc < K; kc += 32) {
    for (int t = threadIdx.x; t < 32*128; t += 256) {
      int kk = t >> 7, cc = t & 127;
      int gk = kc + kk;
      Ws[kk][cc] = (gk < K) ? W[(size_t)gk*128 + cc] : 0.f;
    }
    for (int t = threadIdx.x; t < 16*32; t += 256) {
      int rr = t >> 5, kk = t & 31;
      int gr = r0 + rr, gk = kc + kk;
      As[rr][kk] = (gr < n && gk < K) ? A[(size_t)gr*K + gk] : 0.f;
    }
    __syncthreads();
    #pragma unroll 8
    for (int kk = 0; kk < 32; ++kk) {
      float a = As[row][kk];
      #pragma unroll
      for (int j = 0; j < 8; ++j)
        acc[j] = fmaf(a, Ws[kk][cg + 16*j], acc[j]);
    }
    __syncthreads();
  }
  int gr = r0 + row;
  if (gr < n) {
    float ps = 0.f, pd = 0.f;
    #pragma unroll
    for (int j = 0; j < 8; ++j) {
      int cc = cg + 16*j;
      C[(size_t)gr*128 + cc] = acc[j];
      ps = fmaf(acc[j], a_s[cc], ps);
      pd = fmaf(acc[j], a_d[cc], pd);
    }
    #pragma unroll
    for (int o = 1; o < 16; o <<= 1) {
      ps += __shfl_xor(ps, o);
      pd += __shfl_xor(pd, o);
    }
    if (cg == 0) { zs[gr] = ps; zd[gr] = pd; }
  }
}

// ---------------- per-destination GAT aggregation (one wave per dst) ----------------
__global__ void k_agg(const float* __restrict__ xp, const float* __restrict__ zs,
                      const float* __restrict__ zd, const int* __restrict__ elist,
                      const int* __restrict__ off, float* __restrict__ hacc, int n)
{
  int wid = (int)((blockIdx.x*(size_t)blockDim.x + threadIdx.x) >> 6);
  int lane = threadIdx.x & 63;
  if (wid >= n) return;
  int o0 = off[wid], o1 = off[wid+1];
  int deg = o1 - o0;
  if (deg <= 0) return;
  float zdd = zd[wid];
  float m = -3.4e38f;
  for (int i = lane; i < deg; i += 64) {
    float z = zs[elist[o0 + i]] + zdd;
    z = (z > 0.f) ? z : 0.2f*z;
    m = fmaxf(m, z);
  }
  #pragma unroll
  for (int o = 32; o > 0; o >>= 1) m = fmaxf(m, __shfl_xor(m, o));
  float acc0 = 0.f, acc1 = 0.f, esum = 0.f;
  for (int i = 0; i < deg; ++i) {
    int s = elist[o0 + i];
    float z = zs[s] + zdd;
    z = (z > 0.f) ? z : 0.2f*z;
    float e = expf(z - m);
    esum += e;
    float2 v = *(const float2*)(xp + (size_t)s*HH + lane*2);
    acc0 = fmaf(e, v.x, acc0);
    acc1 = fmaf(e, v.y, acc1);
  }
  float inv = 1.f / esum;
  float* o = hacc + (size_t)wid*HH + lane*2;
  o[0] += acc0 * inv;
  o[1] += acc1 * inv;
}

// ---------------- bias-sum ----------------
__global__ void k_bsum(const float* __restrict__ b, float* __restrict__ bs)
{
  int t = threadIdx.x;
  float s = 0.f;
  #pragma unroll
  for (int r = 0; r < RR; ++r) s += b[r*HH + t];
  bs[t] = s;
}

// ---------------- gelu(exact) + LayerNorm, one wave per row ----------------
__global__ void k_postln(const float* __restrict__ X, float* __restrict__ Y,
                         const float* __restrict__ bsum,
                         const float* __restrict__ nw, const float* __restrict__ nb, int n)
{
  int wid = (int)((blockIdx.x*(size_t)blockDim.x + threadIdx.x) >> 6);
  int lane = threadIdx.x & 63;
  if (wid >= n) return;
  float2 x = *(const float2*)(X + (size_t)wid*HH + lane*2);
  x.x += bsum[lane*2];
  x.y += bsum[lane*2+1];
  float g0 = 0.5f*x.x*(1.f + erff(x.x*0.70710678118654752f));
  float g1 = 0.5f*x.y*(1.f + erff(x.y*0.70710678118654752f));
  float s = g0 + g1;
  #pragma unroll
  for (int o = 32; o > 0; o >>= 1) s += __shfl_xor(s, o);
  float mu = s * (1.f/128.f);
  float d0 = g0 - mu, d1 = g1 - mu;
  float v = d0*d0 + d1*d1;
  #pragma unroll
  for (int o = 32; o > 0; o >>= 1) v += __shfl_xor(v, o);
  v *= (1.f/128.f);
  float inv = 1.f / sqrtf(v + 1e-5f);
  float2 y;
  y.x = d0*inv*nw[lane*2]   + nb[lane*2];
  y.y = d1*inv*nw[lane*2+1] + nb[lane*2+1];
  *(float2*)(Y + (size_t)wid*HH + lane*2) = y;
}

// ---------------- pooling ----------------
__global__ void k_score(const float* __restrict__ X, const float* __restrict__ q,
                        const int* __restrict__ batch, float* __restrict__ scores,
                        unsigned* __restrict__ bmax, int n)
{
  int wid = (int)((blockIdx.x*(size_t)blockDim.x + threadIdx.x) >> 6);
  int lane = threadIdx.x & 63;
  if (wid >= n) return;
  float2 x = *(const float2*)(X + (size_t)wid*HH + lane*2);
  float s = x.x*q[lane*2] + x.y*q[lane*2+1];
  #pragma unroll
  for (int o = 32; o > 0; o >>= 1) s += __shfl_xor(s, o);
  if (lane == 0) {
    scores[wid] = s;
    atomicMax(&bmax[batch[wid]], fenc(s));
  }
}

__global__ void k_segbounds(const int* __restrict__ batch, int* __restrict__ segst,
                            int n, int numB)
{
  int b = blockIdx.x*256 + threadIdx.x;
  if (b > numB) return;
  int lo = 0, hi = n;
  while (lo < hi) { int mid = (lo+hi) >> 1; if (batch[mid] < b) lo = mid+1; else hi = mid; }
  segst[b] = lo;
}

__global__ void k_pool(const float* __restrict__ X, const float* __restrict__ scores,
                       const int* __restrict__ segst, const unsigned* __restrict__ bmax,
                       float* __restrict__ pool, int numB)
{
  int b = blockIdx.x;
  int t = threadIdx.x;  // 0..127
  int s0 = segst[b], s1 = segst[b+1];
  float m = fdec(bmax[b]);
  float acc = 0.f, esum = 0.f;
  for (int i = s0; i < s1; ++i) {
    float e = expf(scores[i] - m);
    esum += e;
    acc = fmaf(e, X[(size_t)i*HH + t], acc);
  }
  float inv = (s1 > s0) ? 1.f/esum : 0.f;
  pool[(size_t)b*HH + t] = acc * inv;
}

__global__ void k_outgemm(const float* __restrict__ pool, const float* __restrict__ projW,
                          const float* __restrict__ projb, float* __restrict__ out, int numB)
{
  int b = blockIdx.x;
  int j = threadIdx.x;  // 0..127
  __shared__ float p[128];
  p[j] = pool[(size_t)b*HH + j];
  __syncthreads();
  float acc = projb[j];
  #pragma unroll 16
  for (int k = 0; k < 128; ++k) acc = fmaf(p[k], projW[(size_t)k*HH + j], acc);
  out[(size_t)b*HH + j] = acc;
}

// ---------------- launcher ----------------
extern "C" void kernel_launch(void* const* d_in, const int* in_sizes, int n_in,
                              void* d_out, int out_size, void* d_ws, size_t ws_size,
                              hipStream_t stream)
{
  const float* x_all = (const float*)d_in[0];
  const int*   edges = (const int*)d_in[1];
  const int*   batch = (const int*)d_in[2];
  const float* pos_table = (const float*)d_in[3];
  const float* W1  = (const float*)d_in[4];
  const float* as1 = (const float*)d_in[5];
  const float* ad1 = (const float*)d_in[6];
  const float* b1  = (const float*)d_in[7];
  const float* W2  = (const float*)d_in[8];
  const float* as2 = (const float*)d_in[9];
  const float* ad2 = (const float*)d_in[10];
  const float* b2  = (const float*)d_in[11];
  const float* n1w = (const float*)d_in[12];
  const float* n1b = (const float*)d_in[13];
  const float* n2w = (const float*)d_in[14];
  const float* n2b = (const float*)d_in[15];
  const float* query = (const float*)d_in[16];
  const float* projW = (const float*)d_in[17];
  const float* projb = (const float*)d_in[18];
  float* out = (float*)d_out;

  char* p = (char*)d_ws;
  auto alloc = [&](size_t b){ void* r = (void*)p; p += (b + 255) & ~(size_t)255; return r; };
  int*   off   = (int*)alloc((size_t)(MM+1)*sizeof(int));
  int*   cur   = (int*)alloc((size_t)MM*sizeof(int));
  int*   elist = (int*)alloc((size_t)RR*EE*sizeof(int));
  int*   bsums = (int*)alloc(1024*sizeof(int));
  float* x0    = (float*)alloc((size_t)NN*DD1*sizeof(float));
  float* xp    = (float*)alloc((size_t)NN*HH*sizeof(float));
  float* zs    = (float*)alloc((size_t)NN*sizeof(float));
  float* zd    = (float*)alloc((size_t)NN*sizeof(float));
  float* hacc  = (float*)alloc((size_t)NN*HH*sizeof(float));
  float* hbuf  = (float*)alloc((size_t)NN*HH*sizeof(float));
  float* bsv   = (float*)alloc(128*sizeof(float));
  int*   segst = (int*)alloc((size_t)(BB+1)*sizeof(int));
  unsigned* bmax = (unsigned*)alloc((size_t)BB*sizeof(unsigned));
  float* pool  = (float*)alloc((size_t)BB*HH*sizeof(float));
  (void)ws_size; (void)in_sizes; (void)n_in; (void)out_size;

  // --- CSR by destination (per relation), rebuilt every call ---
  hipMemsetAsync(cur, 0, (size_t)MM*sizeof(int), stream);
  k_count<<<ceil_div(RR*EE,256),256,0,stream>>>(edges, cur);
  int NB = ceil_div(MM, SCB*SCI);
  k_scan1<<<NB,SCB,0,stream>>>(cur, off, bsums, MM);
  k_scan2<<<1,SCB,0,stream>>>(bsums, NB);
  k_scan3<<<ceil_div(MM,256),256,0,stream>>>(off, bsums, MM, RR*EE);
  hipMemsetAsync(cur, 0, (size_t)MM*sizeof(int), stream);
  k_scatter<<<ceil_div(RR*EE,256),256,0,stream>>>(edges, off, cur, elist);

  // --- feature prep ---
  k_featprep<<<ceil_div(NN*DD1,256),256,0,stream>>>(x_all, pos_table, x0);

  // --- layer 1 ---
  hipMemsetAsync(hacc, 0, (size_t)NN*HH*sizeof(float), stream);
  for (int r = 0; r < RR; ++r) {
    k_gemm_att<<<ceil_div(NN,16),256,0,stream>>>(x0, W1 + (size_t)r*DD1*HH,
                                                 as1 + r*HH, ad1 + r*HH, xp, zs, zd, NN, DD1);
    k_agg<<<ceil_div(NN*64,256),256,0,stream>>>(xp, zs, zd, elist, off + r*NN, hacc, NN);
  }
  k_bsum<<<1,128,0,stream>>>(b1, bsv);
  k_postln<<<ceil_div(NN,4),256,0,stream>>>(hacc, hbuf, bsv, n1w, n1b, NN);

  // --- layer 2 ---
  hipMemsetAsync(hacc, 0, (size_t)NN*HH*sizeof(float), stream);
  for (int r = 0; r < RR; ++r) {
    k_gemm_att<<<ceil_div(NN,16),256,0,stream>>>(hbuf, W2 + (size_t)r*HH*HH,
                                                 as2 + r*HH, ad2 + r*HH, xp, zs, zd, NN, HH);
    k_agg<<<ceil_div(NN*64,256),256,0,stream>>>(xp, zs, zd, elist, off + r*NN, hacc, NN);
  }
  k_bsum<<<1,128,0,stream>>>(b2, bsv);
  k_postln<<<ceil_div(NN,4),256,0,stream>>>(hacc, xp, bsv, n2w, n2b, NN);  // h2 -> xp

  // --- attention pooling ---
  hipMemsetAsync(bmax, 0, (size_t)BB*sizeof(unsigned), stream);
  k_score<<<ceil_div(NN,4),256,0,stream>>>(xp, query, batch, zs, bmax, NN);
  k_segbounds<<<ceil_div(BB+1,256),256,0,stream>>>(batch, segst, NN, BB);
  k_pool<<<BB,128,0,stream>>>(xp, zs, segst, bmax, pool, BB);
  k_outgemm<<<BB,128,0,stream>>>(pool, projW, projb, out, BB);
}